// Round 1
// baseline (456.741 us; speedup 1.0000x reference)
//
#include <hip/hip_runtime.h>
#include <hip/hip_bf16.h>

// MemoryCore: p = softmax_k(keys @ q / sqrt(De)); mem = mo @ p; out = [mem; q_out], p
// B=8 T=4 De=128 Do=512 H=W=32 -> THW=4096 HW=1024
//
// Pipeline:
//  1) memset Z (column sums) in ws
//  2) gemm1: E[k,n] = exp(scale * keys@qi)  (split-bf16 MFMA, ~fp32 accurate)
//     + per-column atomicAdd into Z          E lives in d_out's p region (fp32)
//  3) gemm2: mem[d,n] = (mo @ E)[d,n] / Z[n] (plain bf16 MFMA, ~0.3% rel)
//  4) finalize: p = E / Z in place; copy q_out into mem_out rows 512..1023

typedef short bf16x8 __attribute__((ext_vector_type(8)));
typedef float f32x4  __attribute__((ext_vector_type(4)));

static __device__ __forceinline__ short f2bf(float x) {
  // RNE truncate fp32 -> bf16 bits (finite inputs only)
  unsigned int u = __float_as_uint(x);
  u += 0x7FFFu + ((u >> 16) & 1u);
  return (short)(u >> 16);
}
static __device__ __forceinline__ float bf2f(short s) {
  return __uint_as_float(((unsigned int)(unsigned short)s) << 16);
}
static __device__ __forceinline__ f32x4 mfma16(bf16x8 a, bf16x8 b, f32x4 c) {
  return __builtin_amdgcn_mfma_f32_16x16x32_bf16(a, b, c, 0, 0, 0);
}

// ---------------------------------------------------------------------------
// GEMM1: E = exp(scale * keys @ qi), keys[k,d] = m_in[b, k>>10, d, k&1023]
// block tile 128k x 128n, K=De=128 in 4 chunks of 32, split-bf16 (3 MFMA/term)
// ---------------------------------------------------------------------------
__global__ __launch_bounds__(256) void gemm1_kernel(
    const float* __restrict__ m_in, const float* __restrict__ q_in,
    float* __restrict__ E, float* __restrict__ Z)
{
  const int b   = blockIdx.z;
  const int n0  = blockIdx.x * 128;
  const int k0  = blockIdx.y * 128;
  const int t   = k0 >> 10;
  const int hw0 = k0 & 1023;
  const int tid = threadIdx.x;
  const int lane = tid & 63;
  const int wid  = tid >> 6;
  const int wr = wid >> 1, wc = wid & 1;   // wave = 64x64 subtile

  __shared__ __align__(16) short Ah[128*32], Al[128*32], Bh[128*32], Bl[128*32];

  const float* Ab = m_in + ((size_t)(b*4 + t) * 128) * 1024 + hw0; // + d*1024 + row
  const float* Bb = q_in + ((size_t)b * 128) * 1024 + n0;          // + d*1024 + row

  f32x4 acc[4][4] = {};

  const int srow = tid & 127;          // staged row (k-row for A, n-row for B)
  const int g0   = (tid >> 7) * 2;     // granule pair of 4
  const int swz  = (srow ^ (srow >> 2)) & 3;

  float av[2][8], bv[2][8];
  #pragma unroll
  for (int gi = 0; gi < 2; ++gi) {     // prologue d0 = 0
    const float* ap = Ab + (size_t)((g0 + gi) * 8) * 1024 + srow;
    const float* bp = Bb + (size_t)((g0 + gi) * 8) * 1024 + srow;
    #pragma unroll
    for (int j = 0; j < 8; ++j) { av[gi][j] = ap[(size_t)j*1024]; bv[gi][j] = bp[(size_t)j*1024]; }
  }

  #pragma unroll
  for (int d0 = 0; d0 < 128; d0 += 32) {
    __syncthreads();                    // previous compute done
    #pragma unroll
    for (int gi = 0; gi < 2; ++gi) {
      const int slot = (g0 + gi) ^ swz;
      bf16x8 vh, vl;
      #pragma unroll
      for (int j = 0; j < 8; ++j) {
        float x = av[gi][j]; short h = f2bf(x);
        vh[j] = h; vl[j] = f2bf(x - bf2f(h));
      }
      *(bf16x8*)&Ah[(srow*4 + slot)*8] = vh;
      *(bf16x8*)&Al[(srow*4 + slot)*8] = vl;
      #pragma unroll
      for (int j = 0; j < 8; ++j) {
        float x = bv[gi][j]; short h = f2bf(x);
        vh[j] = h; vl[j] = f2bf(x - bf2f(h));
      }
      *(bf16x8*)&Bh[(srow*4 + slot)*8] = vh;
      *(bf16x8*)&Bl[(srow*4 + slot)*8] = vl;
    }
    __syncthreads();
    if (d0 + 32 < 128) {               // prefetch next chunk (overlaps compute)
      #pragma unroll
      for (int gi = 0; gi < 2; ++gi) {
        const float* ap = Ab + (size_t)(d0 + 32 + (g0 + gi)*8) * 1024 + srow;
        const float* bp = Bb + (size_t)(d0 + 32 + (g0 + gi)*8) * 1024 + srow;
        #pragma unroll
        for (int j = 0; j < 8; ++j) { av[gi][j] = ap[(size_t)j*1024]; bv[gi][j] = bp[(size_t)j*1024]; }
      }
    }
    bf16x8 a_h[4], a_l[4], b_h[4], b_l[4];
    #pragma unroll
    for (int mf = 0; mf < 4; ++mf) {
      const int row  = wr*64 + mf*16 + (lane & 15);
      const int slot = (lane >> 4) ^ ((row ^ (row >> 2)) & 3);
      a_h[mf] = *(const bf16x8*)&Ah[(row*4 + slot)*8];
      a_l[mf] = *(const bf16x8*)&Al[(row*4 + slot)*8];
    }
    #pragma unroll
    for (int nf = 0; nf < 4; ++nf) {
      const int row  = wc*64 + nf*16 + (lane & 15);
      const int slot = (lane >> 4) ^ ((row ^ (row >> 2)) & 3);
      b_h[nf] = *(const bf16x8*)&Bh[(row*4 + slot)*8];
      b_l[nf] = *(const bf16x8*)&Bl[(row*4 + slot)*8];
    }
    #pragma unroll
    for (int mf = 0; mf < 4; ++mf)
      #pragma unroll
      for (int nf = 0; nf < 4; ++nf) {
        acc[mf][nf] = mfma16(a_l[mf], b_h[nf], acc[mf][nf]);
        acc[mf][nf] = mfma16(a_h[mf], b_l[nf], acc[mf][nf]);
        acc[mf][nf] = mfma16(a_h[mf], b_h[nf], acc[mf][nf]);
      }
  }

  // epilogue: e = exp(scale*s), store fp32 E, column sums -> atomic Z
  const float scale = 0.088388347648318447f;   // 1/sqrt(128)
  float cs[4] = {0.f, 0.f, 0.f, 0.f};
  float* Eb = E + (size_t)b * (4096*1024);
  #pragma unroll
  for (int mf = 0; mf < 4; ++mf) {
    const int row = k0 + wr*64 + mf*16 + ((lane >> 4) << 2);
    #pragma unroll
    for (int nf = 0; nf < 4; ++nf) {
      const int col = n0 + wc*64 + nf*16 + (lane & 15);
      float* pp = Eb + (size_t)row * 1024 + col;
      #pragma unroll
      for (int r = 0; r < 4; ++r) {
        float e = __expf(acc[mf][nf][r] * scale);
        pp[(size_t)r * 1024] = e;
        cs[nf] += e;
      }
    }
  }
  #pragma unroll
  for (int nf = 0; nf < 4; ++nf) {
    cs[nf] += __shfl_xor(cs[nf], 16);
    cs[nf] += __shfl_xor(cs[nf], 32);
  }
  if (lane < 16) {
    #pragma unroll
    for (int nf = 0; nf < 4; ++nf)
      atomicAdd(&Z[b*1024 + n0 + wc*64 + nf*16 + lane], cs[nf]);
  }
}

// ---------------------------------------------------------------------------
// GEMM2: mem[d,n] = (mo @ E)/Z ; mo[d,k] = m_out flat [b, d*4096+k]
// block tile 128d x 128n, BK=64 (2 MFMA k-steps), plain bf16
// ---------------------------------------------------------------------------
__global__ __launch_bounds__(256) void gemm2_kernel(
    const float* __restrict__ mo, const float* __restrict__ E,
    const float* __restrict__ Z, float* __restrict__ out)
{
  const int b  = blockIdx.z;
  const int n0 = blockIdx.x * 128;
  const int d0 = blockIdx.y * 128;
  const int tid = threadIdx.x;
  const int lane = tid & 63;
  const int wid  = tid >> 6;
  const int wr = wid >> 1, wc = wid & 1;

  __shared__ __align__(16) short As[128*64];  // [d][k] granule-swizzled
  __shared__ __align__(16) short Bs[128*64];  // [n][k] granule-swizzled

  const float* moB = mo + (size_t)b * (512*4096);
  const float* EB  = E  + (size_t)b * (4096*1024);

  f32x4 acc[4][4] = {};

  const int am  = tid >> 1;            // A staging row (d), 32 contiguous k
  const int ak  = (tid & 1) * 32;
  const int bn  = tid & 127;           // B staging row (n), 4 granules (transposed)
  const int bg0 = (tid >> 7) * 4;

  f32x4 avv[8];
  float bvv[4][8];
  {
    const float* ap = moB + (size_t)(d0 + am) * 4096 + ak;
    #pragma unroll
    for (int q = 0; q < 8; ++q) avv[q] = *(const f32x4*)(ap + q*4);
    #pragma unroll
    for (int g = 0; g < 4; ++g) {
      const float* bp = EB + (size_t)((bg0 + g) * 8) * 1024 + n0 + bn;
      #pragma unroll
      for (int j = 0; j < 8; ++j) bvv[g][j] = bp[(size_t)j*1024];
    }
  }

  for (int k0 = 0; k0 < 4096; k0 += 64) {
    __syncthreads();
    #pragma unroll
    for (int g = 0; g < 4; ++g) {
      const int slot = (ak/8 + g) ^ (am & 7);
      bf16x8 v;
      #pragma unroll
      for (int j = 0; j < 8; ++j) v[j] = f2bf(avv[g*2 + (j>>2)][j&3]);
      *(bf16x8*)&As[(am*8 + slot)*8] = v;
    }
    #pragma unroll
    for (int g = 0; g < 4; ++g) {
      const int slot = (bg0 + g) ^ (bn & 7);
      bf16x8 v;
      #pragma unroll
      for (int j = 0; j < 8; ++j) v[j] = f2bf(bvv[g][j]);
      *(bf16x8*)&Bs[(bn*8 + slot)*8] = v;
    }
    __syncthreads();
    if (k0 + 64 < 4096) {              // prefetch next K-tile into regs
      const float* ap = moB + (size_t)(d0 + am) * 4096 + (k0 + 64) + ak;
      #pragma unroll
      for (int q = 0; q < 8; ++q) avv[q] = *(const f32x4*)(ap + q*4);
      #pragma unroll
      for (int g = 0; g < 4; ++g) {
        const float* bp = EB + (size_t)(k0 + 64 + (bg0 + g)*8) * 1024 + n0 + bn;
        #pragma unroll
        for (int j = 0; j < 8; ++j) bvv[g][j] = bp[(size_t)j*1024];
      }
    }
    #pragma unroll
    for (int kk = 0; kk < 2; ++kk) {
      bf16x8 af[4], bfr[4];
      #pragma unroll
      for (int mf = 0; mf < 4; ++mf) {
        const int row  = wr*64 + mf*16 + (lane & 15);
        const int slot = (kk*4 + (lane >> 4)) ^ (row & 7);
        af[mf] = *(const bf16x8*)&As[(row*8 + slot)*8];
      }
      #pragma unroll
      for (int nf = 0; nf < 4; ++nf) {
        const int row  = wc*64 + nf*16 + (lane & 15);
        const int slot = (kk*4 + (lane >> 4)) ^ (row & 7);
        bfr[nf] = *(const bf16x8*)&Bs[(row*8 + slot)*8];
      }
      #pragma unroll
      for (int mf = 0; mf < 4; ++mf)
        #pragma unroll
        for (int nf = 0; nf < 4; ++nf)
          acc[mf][nf] = mfma16(af[mf], bfr[nf], acc[mf][nf]);
    }
  }

  float rz[4]; int col[4];
  #pragma unroll
  for (int nf = 0; nf < 4; ++nf) {
    col[nf] = n0 + wc*64 + nf*16 + (lane & 15);
    rz[nf]  = 1.0f / Z[b*1024 + col[nf]];
  }
  float* ob = out + (size_t)b * (1024*1024);
  #pragma unroll
  for (int mf = 0; mf < 4; ++mf) {
    const int row = d0 + wr*64 + mf*16 + ((lane >> 4) << 2);
    #pragma unroll
    for (int nf = 0; nf < 4; ++nf) {
      #pragma unroll
      for (int r = 0; r < 4; ++r)
        ob[(size_t)(row + r) * 1024 + col[nf]] = acc[mf][nf][r] * rz[nf];
    }
  }
}

// ---------------------------------------------------------------------------
// finalize: p = E / Z (in place), and copy q_out -> mem_out rows 512..1023
// ---------------------------------------------------------------------------
__global__ __launch_bounds__(256) void finalize_kernel(
    float* __restrict__ p, const float* __restrict__ Z,
    const float* __restrict__ q_out, float* __restrict__ out)
{
  const int NP4 = 8388608;            // p region float4s (8*4096*1024/4)
  const int NT  = 9437184;            // + q_out float4s (8*512*1024/4)
  f32x4* p4 = (f32x4*)p;
  const f32x4* q4 = (const f32x4*)q_out;
  f32x4* o4 = (f32x4*)out;
  for (int i = blockIdx.x*256 + threadIdx.x; i < NT; i += gridDim.x*256) {
    if (i < NP4) {
      const int b  = i >> 20;         // 4096*1024/4 = 2^20 per b
      const int nq = i & 255;         // (i*4) & 1023 -> n = nq*4
      f32x4 e = p4[i];
      f32x4 z = *(const f32x4*)&Z[b*1024 + nq*4];
      p4[i] = e / z;
    } else {
      const int j = i - NP4;
      const int b = j >> 17;          // 512*1024/4 = 2^17 per b
      const int rem = j & 131071;
      o4[(size_t)b*262144 + 131072 + rem] = q4[j];
    }
  }
}

extern "C" void kernel_launch(void* const* d_in, const int* in_sizes, int n_in,
                              void* d_out, int out_size, void* d_ws, size_t ws_size,
                              hipStream_t stream) {
  const float* m_in  = (const float*)d_in[0];
  const float* m_out = (const float*)d_in[1];
  const float* q_in  = (const float*)d_in[2];
  const float* q_out = (const float*)d_in[3];
  float* out = (float*)d_out;
  float* E   = out + (size_t)8*1024*1024;   // p region holds E, finalized in place
  float* Z   = (float*)d_ws;                // 8*1024 column sums

  hipMemsetAsync(Z, 0, 8*1024*sizeof(float), stream);
  gemm1_kernel<<<dim3(8, 32, 8), 256, 0, stream>>>(m_in, q_in, E, Z);
  gemm2_kernel<<<dim3(8, 4, 8), 256, 0, stream>>>(m_out, E, Z, out);
  finalize_kernel<<<4608, 256, 0, stream>>>(E, Z, q_out, out);
}

// Round 2
// 455.448 us; speedup vs baseline: 1.0028x; 1.0028x over previous
//
#include <hip/hip_runtime.h>
#include <hip/hip_bf16.h>
#include <hip/hip_fp16.h>

// MemoryCore: p = softmax_k(keys @ q / sqrt(De)); mem = mo @ p; out = [mem; q_out], p
// B=8 T=4 De=128 Do=512 H=W=32 -> THW=4096 (k), HW=1024 (n)
//
// Pipeline (all fp16 MFMA, fp32 accumulate):
//  1) zero: mem-accumulator region of d_out + Z
//  2) gemm1: E[k,n] = exp(scale * keys@qi) fp32 (fp16 MFMA), Z[n] += col-sums
//  3) gemm2: memacc[d,n] += mo @ E  (fp16 MFMA, split-K x4, fp32 atomics)
//  4) finalize: p = E/Z in place; mem = memacc/Z; copy q_out

typedef _Float16 f16x8 __attribute__((ext_vector_type(8)));
typedef float    f32x4 __attribute__((ext_vector_type(4)));

static __device__ __forceinline__ f32x4 mfma16h(f16x8 a, f16x8 b, f32x4 c) {
  return __builtin_amdgcn_mfma_f32_16x16x32_f16(a, b, c, 0, 0, 0);
}

// ---------------------------------------------------------------------------
// zero: mem region (8 x 512 x 1024 floats at stride 1M floats) + Z (8192)
// ---------------------------------------------------------------------------
__global__ __launch_bounds__(256) void zero_kernel(float* __restrict__ out,
                                                   float* __restrict__ Z) {
  const int NM = 1048576;              // mem f32x4 count (8*512*1024/4)
  const f32x4 zv = {0.f, 0.f, 0.f, 0.f};
  for (int i = blockIdx.x*256 + threadIdx.x; i < NM + 2048; i += gridDim.x*256) {
    if (i < NM) {
      const int b = i >> 17;           // 131072 f32x4 per b
      const int rem = i & 131071;
      ((f32x4*)out)[(size_t)b*262144 + rem] = zv;
    } else {
      ((f32x4*)Z)[i - NM] = zv;
    }
  }
}

// ---------------------------------------------------------------------------
// GEMM1: E = exp(scale * keys @ qi), keys[k,d] = m_in[b, k>>10, d, k&1023]
// block tile 128k x 128n, K=De=128 in 4 chunks of 32, single fp16
// ---------------------------------------------------------------------------
__global__ __launch_bounds__(256) void gemm1_kernel(
    const float* __restrict__ m_in, const float* __restrict__ q_in,
    float* __restrict__ E, float* __restrict__ Z)
{
  const int b   = blockIdx.z;
  const int n0  = blockIdx.x * 128;
  const int k0  = blockIdx.y * 128;
  const int t   = k0 >> 10;
  const int hw0 = k0 & 1023;
  const int tid = threadIdx.x;
  const int lane = tid & 63;
  const int wid  = tid >> 6;
  const int wr = wid >> 1, wc = wid & 1;   // wave = 64x64 subtile

  __shared__ __align__(16) _Float16 Ah[128*32], Bh[128*32];   // 8 KB each

  const float* Ab = m_in + ((size_t)(b*4 + t) * 128) * 1024 + hw0; // + d*1024 + row
  const float* Bb = q_in + ((size_t)b * 128) * 1024 + n0;          // + d*1024 + row

  f32x4 acc[4][4] = {};

  const int srow = tid & 127;          // staged row (k-row for A, n-row for B)
  const int g0   = (tid >> 7) * 2;     // granule pair of 4
  const int swz  = (srow ^ (srow >> 2)) & 3;

  float av[2][8], bv[2][8];
  #pragma unroll
  for (int gi = 0; gi < 2; ++gi) {     // prologue d0 = 0
    const float* ap = Ab + (size_t)((g0 + gi) * 8) * 1024 + srow;
    const float* bp = Bb + (size_t)((g0 + gi) * 8) * 1024 + srow;
    #pragma unroll
    for (int j = 0; j < 8; ++j) { av[gi][j] = ap[(size_t)j*1024]; bv[gi][j] = bp[(size_t)j*1024]; }
  }

  #pragma unroll
  for (int d0 = 0; d0 < 128; d0 += 32) {
    __syncthreads();                    // previous compute done
    #pragma unroll
    for (int gi = 0; gi < 2; ++gi) {
      const int slot = (g0 + gi) ^ swz;
      f16x8 vh, wh;
      #pragma unroll
      for (int j = 0; j < 8; ++j) {
        vh[j] = (_Float16)av[gi][j];
        wh[j] = (_Float16)bv[gi][j];
      }
      *(f16x8*)&Ah[(srow*4 + slot)*8] = vh;
      *(f16x8*)&Bh[(srow*4 + slot)*8] = wh;
    }
    __syncthreads();
    if (d0 + 32 < 128) {               // prefetch next chunk (overlaps compute)
      #pragma unroll
      for (int gi = 0; gi < 2; ++gi) {
        const float* ap = Ab + (size_t)(d0 + 32 + (g0 + gi)*8) * 1024 + srow;
        const float* bp = Bb + (size_t)(d0 + 32 + (g0 + gi)*8) * 1024 + srow;
        #pragma unroll
        for (int j = 0; j < 8; ++j) { av[gi][j] = ap[(size_t)j*1024]; bv[gi][j] = bp[(size_t)j*1024]; }
      }
    }
    f16x8 a_h[4], b_h[4];
    #pragma unroll
    for (int mf = 0; mf < 4; ++mf) {
      const int row  = wr*64 + mf*16 + (lane & 15);
      const int slot = (lane >> 4) ^ ((row ^ (row >> 2)) & 3);
      a_h[mf] = *(const f16x8*)&Ah[(row*4 + slot)*8];
    }
    #pragma unroll
    for (int nf = 0; nf < 4; ++nf) {
      const int row  = wc*64 + nf*16 + (lane & 15);
      const int slot = (lane >> 4) ^ ((row ^ (row >> 2)) & 3);
      b_h[nf] = *(const f16x8*)&Bh[(row*4 + slot)*8];
    }
    #pragma unroll
    for (int mf = 0; mf < 4; ++mf)
      #pragma unroll
      for (int nf = 0; nf < 4; ++nf)
        acc[mf][nf] = mfma16h(a_h[mf], b_h[nf], acc[mf][nf]);
  }

  // epilogue: e = exp(scale*s), store fp32 E, column sums -> atomic Z
  const float scale = 0.088388347648318447f;   // 1/sqrt(128)
  float cs[4] = {0.f, 0.f, 0.f, 0.f};
  float* Eb = E + (size_t)b * (4096*1024);
  #pragma unroll
  for (int mf = 0; mf < 4; ++mf) {
    const int row = k0 + wr*64 + mf*16 + ((lane >> 4) << 2);
    #pragma unroll
    for (int nf = 0; nf < 4; ++nf) {
      const int col = n0 + wc*64 + nf*16 + (lane & 15);
      float* pp = Eb + (size_t)row * 1024 + col;
      #pragma unroll
      for (int r = 0; r < 4; ++r) {
        float e = __expf(acc[mf][nf][r] * scale);
        pp[(size_t)r * 1024] = e;
        cs[nf] += e;
      }
    }
  }
  #pragma unroll
  for (int nf = 0; nf < 4; ++nf) {
    cs[nf] += __shfl_xor(cs[nf], 16);
    cs[nf] += __shfl_xor(cs[nf], 32);
  }
  if (lane < 16) {
    #pragma unroll
    for (int nf = 0; nf < 4; ++nf)
      atomicAdd(&Z[b*1024 + n0 + wc*64 + nf*16 + lane], cs[nf]);
  }
}

// ---------------------------------------------------------------------------
// GEMM2: memacc[d,n] += mo @ E ; mo[d,k] = m_out flat [b, d*4096+k]
// block tile 128d x 128n, split-K x4 (1024 k each), BK=64, fp16 MFMA
// grid: x = n-tile(8), y = d-tile(4)*4 + ks(4), z = b(8)
// ---------------------------------------------------------------------------
__global__ __launch_bounds__(256) void gemm2_kernel(
    const float* __restrict__ mo, const float* __restrict__ E,
    float* __restrict__ memacc)
{
  const int b  = blockIdx.z;
  const int n0 = blockIdx.x * 128;
  const int d0 = (blockIdx.y >> 2) * 128;
  const int ks = blockIdx.y & 3;
  const int kbeg = ks * 1024;
  const int kend = kbeg + 1024;
  const int tid = threadIdx.x;
  const int lane = tid & 63;
  const int wid  = tid >> 6;
  const int wr = wid >> 1, wc = wid & 1;

  __shared__ __align__(16) _Float16 As[128*64];  // [d][k] granule-swizzled, 16 KB
  __shared__ __align__(16) _Float16 Bs[128*64];  // [n][k] granule-swizzled, 16 KB

  const float* moB = mo + (size_t)b * (512*4096);
  const float* EB  = E  + (size_t)b * (4096*1024);

  f32x4 acc[4][4] = {};

  const int am  = tid >> 1;            // A staging row (d), 32 contiguous k
  const int ak  = (tid & 1) * 32;
  const int bn  = tid & 127;           // B staging row (n), 4 granules (transposed)
  const int bg0 = (tid >> 7) * 4;

  f32x4 avv[8];
  float bvv[4][8];
  {
    const float* ap = moB + (size_t)(d0 + am) * 4096 + kbeg + ak;
    #pragma unroll
    for (int q = 0; q < 8; ++q) avv[q] = *(const f32x4*)(ap + q*4);
    #pragma unroll
    for (int g = 0; g < 4; ++g) {
      const float* bp = EB + (size_t)(kbeg + (bg0 + g) * 8) * 1024 + n0 + bn;
      #pragma unroll
      for (int j = 0; j < 8; ++j) bvv[g][j] = bp[(size_t)j*1024];
    }
  }

  for (int k0 = kbeg; k0 < kend; k0 += 64) {
    __syncthreads();
    #pragma unroll
    for (int g = 0; g < 4; ++g) {
      const int slot = (ak/8 + g) ^ (am & 7);
      f16x8 v;
      #pragma unroll
      for (int j = 0; j < 8; ++j) v[j] = (_Float16)(avv[g*2 + (j>>2)][j&3]);
      *(f16x8*)&As[(am*8 + slot)*8] = v;
    }
    #pragma unroll
    for (int g = 0; g < 4; ++g) {
      const int slot = (bg0 + g) ^ (bn & 7);
      f16x8 v;
      #pragma unroll
      for (int j = 0; j < 8; ++j) v[j] = (_Float16)(bvv[g][j]);
      *(f16x8*)&Bs[(bn*8 + slot)*8] = v;
    }
    __syncthreads();
    if (k0 + 64 < kend) {              // prefetch next K-tile into regs
      const float* ap = moB + (size_t)(d0 + am) * 4096 + (k0 + 64) + ak;
      #pragma unroll
      for (int q = 0; q < 8; ++q) avv[q] = *(const f32x4*)(ap + q*4);
      #pragma unroll
      for (int g = 0; g < 4; ++g) {
        const float* bp = EB + (size_t)(k0 + 64 + (bg0 + g)*8) * 1024 + n0 + bn;
        #pragma unroll
        for (int j = 0; j < 8; ++j) bvv[g][j] = bp[(size_t)j*1024];
      }
    }
    #pragma unroll
    for (int kk = 0; kk < 2; ++kk) {
      f16x8 af[4], bfr[4];
      #pragma unroll
      for (int mf = 0; mf < 4; ++mf) {
        const int row  = wr*64 + mf*16 + (lane & 15);
        const int slot = (kk*4 + (lane >> 4)) ^ (row & 7);
        af[mf] = *(const f16x8*)&As[(row*8 + slot)*8];
      }
      #pragma unroll
      for (int nf = 0; nf < 4; ++nf) {
        const int row  = wc*64 + nf*16 + (lane & 15);
        const int slot = (kk*4 + (lane >> 4)) ^ (row & 7);
        bfr[nf] = *(const f16x8*)&Bs[(row*8 + slot)*8];
      }
      #pragma unroll
      for (int mf = 0; mf < 4; ++mf)
        #pragma unroll
        for (int nf = 0; nf < 4; ++nf)
          acc[mf][nf] = mfma16h(af[mf], bfr[nf], acc[mf][nf]);
    }
  }

  // epilogue: accumulate partial products (split-K) into zeroed memacc
  float* ob = memacc + (size_t)b * (1024*1024);
  #pragma unroll
  for (int mf = 0; mf < 4; ++mf) {
    const int row = d0 + wr*64 + mf*16 + ((lane >> 4) << 2);
    #pragma unroll
    for (int nf = 0; nf < 4; ++nf) {
      const int col = n0 + wc*64 + nf*16 + (lane & 15);
      #pragma unroll
      for (int r = 0; r < 4; ++r)
        atomicAdd(&ob[(size_t)(row + r) * 1024 + col], acc[mf][nf][r]);
    }
  }
}

// ---------------------------------------------------------------------------
// finalize: p = E/Z (in place), mem = memacc/Z, copy q_out -> rows 512..1023
// ---------------------------------------------------------------------------
__global__ __launch_bounds__(256) void finalize_kernel(
    float* __restrict__ p, const float* __restrict__ Z,
    const float* __restrict__ q_out, float* __restrict__ out)
{
  const int NP4 = 8388608;            // p region f32x4 (8*4096*1024/4)
  const int NQ4 = 1048576;            // q_out f32x4   (8*512*1024/4)
  const int NT  = NP4 + 2*NQ4;        // + mem region f32x4
  f32x4* p4 = (f32x4*)p;
  const f32x4* q4 = (const f32x4*)q_out;
  f32x4* o4 = (f32x4*)out;
  const f32x4* Z4 = (const f32x4*)Z;
  for (int i = blockIdx.x*256 + threadIdx.x; i < NT; i += gridDim.x*256) {
    if (i < NP4) {
      const int b  = i >> 20;         // 2^20 f32x4 per b
      const int nq = i & 255;         // n quad
      f32x4 e = p4[i];
      f32x4 z = Z4[b*256 + nq];
      p4[i] = e / z;
    } else if (i < NP4 + NQ4) {
      const int j = i - NP4;
      const int b = j >> 17;          // 2^17 f32x4 per b
      const int rem = j & 131071;
      o4[(size_t)b*262144 + 131072 + rem] = q4[j];
    } else {
      const int j = i - NP4 - NQ4;
      const int b = j >> 17;
      const int rem = j & 131071;
      const int nq = rem & 255;
      f32x4 m = o4[(size_t)b*262144 + rem];
      f32x4 z = Z4[b*256 + nq];
      o4[(size_t)b*262144 + rem] = m / z;
    }
  }
}

extern "C" void kernel_launch(void* const* d_in, const int* in_sizes, int n_in,
                              void* d_out, int out_size, void* d_ws, size_t ws_size,
                              hipStream_t stream) {
  const float* m_in  = (const float*)d_in[0];
  const float* m_out = (const float*)d_in[1];
  const float* q_in  = (const float*)d_in[2];
  const float* q_out = (const float*)d_in[3];
  float* out = (float*)d_out;
  float* E   = out + (size_t)8*1024*1024;   // p region holds E, finalized in place
  float* Z   = (float*)d_ws;                // 8*1024 column sums

  zero_kernel<<<2048, 256, 0, stream>>>(out, Z);
  gemm1_kernel<<<dim3(8, 32, 8), 256, 0, stream>>>(m_in, q_in, E, Z);
  gemm2_kernel<<<dim3(8, 16, 8), 256, 0, stream>>>(m_out, E, out);
  finalize_kernel<<<4608, 256, 0, stream>>>(E, Z, q_out, out);
}

// Round 3
// 391.408 us; speedup vs baseline: 1.1669x; 1.1636x over previous
//
#include <hip/hip_runtime.h>
#include <hip/hip_fp16.h>

// MemoryCore: p = softmax_k(keys @ q / sqrt(De)); mem = mo @ p; out = [mem; q_out], p
// B=8 T=4 De=128 Do=512 H=W=32 -> THW=4096 (k), HW=1024 (n)
//
// Pipeline (all fp16 MFMA, m97-style global_load_lds staging, T2 swizzle):
//  0) memset Z; convert m_out -> moH fp16; transpose m_in -> kH[b][thw][d],
//     q_in -> qT[b][hw][d] fp16
//  1) gemm1: E_t[n][k] = exp(scale * kH@qT^T) fp16 (k-contiguous), Z[n] atomic
//  2) gemm2: P[ks] = moH @ E_t^T partials (split-K, fp32), or direct /Z if ns==1
//  3) finalize_p: p[k][n] = E_t^T / Z (LDS tile transpose)
//     finalize_memq: mem = sum(P)/Z ; copy q_out

typedef _Float16 f16x8 __attribute__((ext_vector_type(8)));
typedef _Float16 f16x4 __attribute__((ext_vector_type(4)));
typedef float    f32x4 __attribute__((ext_vector_type(4)));

static __device__ __forceinline__ f32x4 mfma16h(f16x8 a, f16x8 b, f32x4 c) {
  return __builtin_amdgcn_mfma_f32_16x16x32_f16(a, b, c, 0, 0, 0);
}

// global -> LDS direct DMA, 16B per lane. LDS dest = wave-uniform base + lane*16.
static __device__ __forceinline__ void gload16(const void* g, void* l) {
  __builtin_amdgcn_global_load_lds(
      (const __attribute__((address_space(1))) unsigned int*)(g),
      (__attribute__((address_space(3))) unsigned int*)(l),
      16, 0, 0);
}

// ---------------------------------------------------------------------------
// cast: fp32 -> fp16 straight copy (m_out -> moH)
// ---------------------------------------------------------------------------
__global__ __launch_bounds__(256) void cast_kernel(const float* __restrict__ src,
                                                   _Float16* __restrict__ dst, int n8) {
  for (int i = blockIdx.x*256 + threadIdx.x; i < n8; i += gridDim.x*256) {
    f32x4 a = ((const f32x4*)src)[2*i], b = ((const f32x4*)src)[2*i+1];
    f16x8 v;
    v[0]=(_Float16)a[0]; v[1]=(_Float16)a[1]; v[2]=(_Float16)a[2]; v[3]=(_Float16)a[3];
    v[4]=(_Float16)b[0]; v[5]=(_Float16)b[1]; v[6]=(_Float16)b[2]; v[7]=(_Float16)b[3];
    ((f16x8*)dst)[i] = v;
  }
}

// ---------------------------------------------------------------------------
// transpose_cast: src [slab][128][1024] f32 -> dst [slab][1024][128] fp16
// 64x64 tiles via LDS. grid: x = (row-tile<<4)|col-tile? -> x in [0,32): tx=x&15, ty=x>>4
// ---------------------------------------------------------------------------
__global__ __launch_bounds__(256) void transpose_cast_kernel(
    const float* __restrict__ src, _Float16* __restrict__ dst) {
  __shared__ float T[64][65];
  const int slab = blockIdx.y;
  const int tx = blockIdx.x & 15, ty = blockIdx.x >> 4;
  const int c0 = tx*64, r0 = ty*64;
  const float* s = src + (size_t)slab*131072;
  _Float16*    d = dst + (size_t)slab*131072;
  const int t = threadIdx.x;
  {
    const int rr = t >> 4, cq = t & 15;
    #pragma unroll
    for (int i = 0; i < 4; ++i) {
      f32x4 v = *(const f32x4*)(s + (size_t)(r0 + rr + 16*i)*1024 + c0 + cq*4);
      T[rr+16*i][cq*4+0] = v[0]; T[rr+16*i][cq*4+1] = v[1];
      T[rr+16*i][cq*4+2] = v[2]; T[rr+16*i][cq*4+3] = v[3];
    }
  }
  __syncthreads();
  {
    const int cl = t >> 2, rq = t & 3;
    #pragma unroll
    for (int u = 0; u < 2; ++u) {
      f16x8 v;
      #pragma unroll
      for (int j = 0; j < 8; ++j) v[j] = (_Float16)T[rq*16 + u*8 + j][cl];
      *(f16x8*)(d + (size_t)(c0 + cl)*128 + r0 + rq*16 + u*8) = v;
    }
  }
}

// ---------------------------------------------------------------------------
// GEMM1: E_t[n][k] = exp(scale * (kH @ qT^T)[k][n]), Z[n] += col sums
// kH[b][4096][128], qT[b][1024][128] fp16. tile 128k x 128n, BK=64 over d, 2 iters
// ---------------------------------------------------------------------------
__global__ __launch_bounds__(256) void gemm1_kernel(
    const _Float16* __restrict__ kH, const _Float16* __restrict__ qT,
    _Float16* __restrict__ Et, float* __restrict__ Z) {
  const int b = blockIdx.z, n0 = blockIdx.x*128, k0 = blockIdx.y*128;
  const int tid = threadIdx.x, lane = tid & 63, wid = tid >> 6;
  const int wr = wid >> 1, wc = wid & 1;
  __shared__ __align__(16) _Float16 As[8192], Bs[8192];   // [128][64], swizzled

  const char* Ag = (const char*)(kH + (size_t)b*524288 + (size_t)k0*128); // row stride 256B
  const char* Bg = (const char*)(qT + (size_t)b*131072 + (size_t)n0*128);

  f32x4 acc[4][4] = {};
  const int srow = tid >> 3, ssl = tid & 7;

  for (int dc = 0; dc < 2; ++dc) {
    __syncthreads();
    #pragma unroll
    for (int c = 0; c < 4; ++c) {
      const int row = c*32 + srow;
      const int sg  = ssl ^ (row & 7);           // inverse-swizzled global source
      gload16(Ag + (size_t)row*256 + dc*128 + sg*16, As + c*2048 + wid*512);
      gload16(Bg + (size_t)row*256 + dc*128 + sg*16, Bs + c*2048 + wid*512);
    }
    __syncthreads();                              // drains vmcnt -> LDS ready
    #pragma unroll
    for (int kk = 0; kk < 2; ++kk) {
      f16x8 af[4], bf[4];
      #pragma unroll
      for (int mf = 0; mf < 4; ++mf) {
        const int row = wr*64 + mf*16 + (lane & 15);
        const int u   = kk*4 + (lane >> 4);
        af[mf] = *(const f16x8*)&As[row*64 + ((u ^ (row & 7)) << 3)];
      }
      #pragma unroll
      for (int nf = 0; nf < 4; ++nf) {
        const int row = wc*64 + nf*16 + (lane & 15);
        const int u   = kk*4 + (lane >> 4);
        bf[nf] = *(const f16x8*)&Bs[row*64 + ((u ^ (row & 7)) << 3)];
      }
      #pragma unroll
      for (int mf = 0; mf < 4; ++mf)
        #pragma unroll
        for (int nf = 0; nf < 4; ++nf)
          acc[mf][nf] = mfma16h(af[mf], bf[nf], acc[mf][nf]);
    }
  }

  const float scale = 0.088388347648318447f;   // 1/sqrt(128)
  float cs[4] = {0.f, 0.f, 0.f, 0.f};
  _Float16* Eb = Et + (size_t)b*4194304;
  #pragma unroll
  for (int nf = 0; nf < 4; ++nf) {
    const int n = n0 + wc*64 + nf*16 + (lane & 15);
    #pragma unroll
    for (int mf = 0; mf < 4; ++mf) {
      const int kb = k0 + wr*64 + mf*16 + ((lane >> 4) << 2);  // 4 consecutive k
      f16x4 v;
      #pragma unroll
      for (int r = 0; r < 4; ++r) {
        float e = __expf(acc[mf][nf][r] * scale);
        v[r] = (_Float16)e; cs[nf] += e;
      }
      *(f16x4*)(Eb + (size_t)n*4096 + kb) = v;   // 8B packed store
    }
  }
  #pragma unroll
  for (int nf = 0; nf < 4; ++nf) {
    cs[nf] += __shfl_xor(cs[nf], 16);
    cs[nf] += __shfl_xor(cs[nf], 32);
  }
  if (lane < 16)
    #pragma unroll
    for (int nf = 0; nf < 4; ++nf)
      atomicAdd(&Z[b*1024 + n0 + wc*64 + nf*16 + lane], cs[nf]);
}

// ---------------------------------------------------------------------------
// GEMM2: mem[d][n] = sum_k moH[d][k] * E_t[n][k]. tile 128d x 128n, BK=64.
// split-K: z = b*nsplit + ks; partials to P (fp32), or direct /Z write if ns==1
// ---------------------------------------------------------------------------
__global__ __launch_bounds__(256) void gemm2_kernel(
    const _Float16* __restrict__ moH, const _Float16* __restrict__ Et,
    const float* __restrict__ Z, float* __restrict__ P, float* __restrict__ out,
    int ksteps, int kslog) {
  const int zb = blockIdx.z;
  const int b = zb >> kslog, ks = zb & ((1 << kslog) - 1);
  const int n0 = blockIdx.x*128, d0 = blockIdx.y*128;
  const int tid = threadIdx.x, lane = tid & 63, wid = tid >> 6;
  const int wr = wid >> 1, wc = wid & 1;
  __shared__ __align__(16) _Float16 As[8192], Bs[8192];   // [128][64], swizzled

  const char* Ag = (const char*)(moH + (size_t)b*2097152 + (size_t)d0*4096); // stride 8192B
  const char* Bg = (const char*)(Et  + (size_t)b*4194304 + (size_t)n0*4096);

  f32x4 acc[4][4] = {};
  const int srow = tid >> 3, ssl = tid & 7;
  const int kbeg = ks * ksteps;

  for (int it = 0; it < ksteps; ++it) {
    const size_t kb = (size_t)(kbeg + it) * 128;  // byte offset along k (64 halfs)
    __syncthreads();
    #pragma unroll
    for (int c = 0; c < 4; ++c) {
      const int row = c*32 + srow;
      const int sg  = ssl ^ (row & 7);
      gload16(Ag + (size_t)row*8192 + kb + sg*16, As + c*2048 + wid*512);
      gload16(Bg + (size_t)row*8192 + kb + sg*16, Bs + c*2048 + wid*512);
    }
    __syncthreads();
    #pragma unroll
    for (int kk = 0; kk < 2; ++kk) {
      f16x8 af[4], bf[4];
      #pragma unroll
      for (int mf = 0; mf < 4; ++mf) {
        const int row = wr*64 + mf*16 + (lane & 15);
        const int u   = kk*4 + (lane >> 4);
        af[mf] = *(const f16x8*)&As[row*64 + ((u ^ (row & 7)) << 3)];
      }
      #pragma unroll
      for (int nf = 0; nf < 4; ++nf) {
        const int row = wc*64 + nf*16 + (lane & 15);
        const int u   = kk*4 + (lane >> 4);
        bf[nf] = *(const f16x8*)&Bs[row*64 + ((u ^ (row & 7)) << 3)];
      }
      #pragma unroll
      for (int mf = 0; mf < 4; ++mf)
        #pragma unroll
        for (int nf = 0; nf < 4; ++nf)
          acc[mf][nf] = mfma16h(af[mf], bf[nf], acc[mf][nf]);
    }
  }

  if (kslog == 0) {   // direct write: mem = acc / Z
    float* ob = out + (size_t)b*1048576;
    #pragma unroll
    for (int nf = 0; nf < 4; ++nf) {
      const int col = n0 + wc*64 + nf*16 + (lane & 15);
      const float rz = 1.0f / Z[b*1024 + col];
      #pragma unroll
      for (int mf = 0; mf < 4; ++mf) {
        const int row = d0 + wr*64 + mf*16 + ((lane >> 4) << 2);
        #pragma unroll
        for (int r = 0; r < 4; ++r)
          ob[(size_t)(row + r)*1024 + col] = acc[mf][nf][r] * rz;
      }
    }
  } else {            // partial write (fp32), summed in finalize
    float* pb = P + (size_t)(ks*8 + b)*524288;
    #pragma unroll
    for (int nf = 0; nf < 4; ++nf) {
      const int col = n0 + wc*64 + nf*16 + (lane & 15);
      #pragma unroll
      for (int mf = 0; mf < 4; ++mf) {
        const int row = d0 + wr*64 + mf*16 + ((lane >> 4) << 2);
        #pragma unroll
        for (int r = 0; r < 4; ++r)
          pb[(size_t)(row + r)*1024 + col] = acc[mf][nf][r];
      }
    }
  }
}

// ---------------------------------------------------------------------------
// finalize_p: p[k][n] = E_t[n][k] / Z[n]  (64x64 LDS tile transpose)
// grid: x = kt*16 + nt (1024), y = b
// ---------------------------------------------------------------------------
__global__ __launch_bounds__(256) void finalize_p_kernel(
    const _Float16* __restrict__ Et, const float* __restrict__ Z,
    float* __restrict__ p) {
  __shared__ float T[64][65];
  const int b = blockIdx.y;
  const int kt = blockIdx.x >> 4, nt = blockIdx.x & 15;
  const int k0 = kt*64, n0 = nt*64;
  const _Float16* Eb = Et + (size_t)b*4194304;
  const int t = threadIdx.x;
  {
    const int nl = t >> 2, kc = t & 3;
    #pragma unroll
    for (int u = 0; u < 2; ++u) {
      const int kl = (kc*2 + u)*8;
      f16x8 v = *(const f16x8*)(Eb + (size_t)(n0 + nl)*4096 + k0 + kl);
      #pragma unroll
      for (int j = 0; j < 8; ++j) T[kl + j][nl] = (float)v[j];
    }
  }
  __syncthreads();
  float* pb = p + (size_t)b*4194304;
  {
    const int kr = t >> 2;
    #pragma unroll
    for (int w = 0; w < 4; ++w) {
      const int nq = (t & 3)*4 + w;
      f32x4 z = *(const f32x4*)(Z + b*1024 + n0 + nq*4);
      f32x4 v;
      v[0] = T[kr][nq*4+0]; v[1] = T[kr][nq*4+1];
      v[2] = T[kr][nq*4+2]; v[3] = T[kr][nq*4+3];
      v = v / z;
      *(f32x4*)(pb + (size_t)(k0 + kr)*1024 + n0 + nq*4) = v;
    }
  }
}

// ---------------------------------------------------------------------------
// finalize_memq: mem = sum_j P_j / Z (if nm4>0), copy q_out -> rows 512..1023
// ---------------------------------------------------------------------------
__global__ __launch_bounds__(256) void finalize_memq_kernel(
    const float* __restrict__ P, const float* __restrict__ Z,
    const float* __restrict__ q_out, float* __restrict__ out,
    int nm4, int nsplit) {
  const int NQ4 = 1048576;
  const int total = nm4 + NQ4;
  for (int i = blockIdx.x*256 + threadIdx.x; i < total; i += gridDim.x*256) {
    if (i < nm4) {
      const int b = i >> 17, rem = i & 131071, nq = i & 255;
      f32x4 s = {0.f, 0.f, 0.f, 0.f};
      for (int j = 0; j < nsplit; ++j)
        s += ((const f32x4*)P)[(size_t)(j*8 + b)*131072 + rem];
      f32x4 z = ((const f32x4*)Z)[b*256 + nq];
      ((f32x4*)out)[(size_t)b*262144 + rem] = s / z;
    } else {
      const int jj = i - nm4;
      const int b = jj >> 17, rem = jj & 131071;
      ((f32x4*)out)[(size_t)b*262144 + 131072 + rem] = ((const f32x4*)q_out)[jj];
    }
  }
}

extern "C" void kernel_launch(void* const* d_in, const int* in_sizes, int n_in,
                              void* d_out, int out_size, void* d_ws, size_t ws_size,
                              hipStream_t stream) {
  const float* m_in  = (const float*)d_in[0];
  const float* m_out = (const float*)d_in[1];
  const float* q_in  = (const float*)d_in[2];
  const float* q_out = (const float*)d_in[3];
  float* out = (float*)d_out;
  float* p   = out + (size_t)8*1024*1024;        // p region after mem_out

  char* ws = (char*)d_ws;
  size_t off = 0;
  float*    Z   = (float*)(ws + off);    off += 32768;        // 8*1024 f32 (+pad)
  _Float16* moH = (_Float16*)(ws + off); off += 33554432;     // 8*512*4096 fp16
  _Float16* kH  = (_Float16*)(ws + off); off += 16777216;     // 8*4096*128 fp16
  _Float16* qT  = (_Float16*)(ws + off); off += 2097152;      // 8*1024*128 fp16
  _Float16* Et  = (_Float16*)(ws + off); off += 67108864;     // 8*1024*4096 fp16
  float*    P   = (float*)(ws + off);                         // nsplit*8*512*1024 f32
  const size_t base = off;

  int kslog = 0;
  if (ws_size >= base + 4ull*16777216) kslog = 2;        // nsplit 4
  else if (ws_size >= base + 2ull*16777216) kslog = 1;   // nsplit 2
  const int nsplit = 1 << kslog;
  const int ksteps = 64 >> kslog;                        // K-iters per block

  hipMemsetAsync(Z, 0, 32768, stream);
  cast_kernel<<<2048, 256, 0, stream>>>(m_out, moH, 2097152);
  transpose_cast_kernel<<<dim3(32, 32), 256, 0, stream>>>(m_in, kH);
  transpose_cast_kernel<<<dim3(32, 8),  256, 0, stream>>>(q_in, qT);
  gemm1_kernel<<<dim3(8, 32, 8), 256, 0, stream>>>(kH, qT, Et, Z);
  gemm2_kernel<<<dim3(8, 4, 8 << kslog), 256, 0, stream>>>(moH, Et, Z, P, out, ksteps, kslog);
  finalize_p_kernel<<<dim3(1024, 8), 256, 0, stream>>>(Et, Z, p);
  finalize_memq_kernel<<<2048, 256, 0, stream>>>(P, Z, q_out, out,
                                                 nsplit == 1 ? 0 : 1048576, nsplit);
}